// Round 6
// baseline (186.737 us; speedup 1.0000x reference)
//
#include <hip/hip_runtime.h>
#include <math.h>

#define BB 512
#define TT 1024
#define KK 48
#define SEG 17       // segments per chain; fwd scans = bwd scans = 16 = MFMA columns
#define CENTER 6     // keep |B| centered near 2^-CENTER for f16 headroom

typedef _Float16 f16x8 __attribute__((ext_vector_type(8)));
typedef _Float16 f16x4 __attribute__((ext_vector_type(4)));
typedef float    f32x4 __attribute__((ext_vector_type(4)));

#if __has_builtin(__builtin_amdgcn_mfma_f32_16x16x16f16)
#define HAVE_X16 1
#else
#define HAVE_X16 0
#endif

static constexpr float L2E = 1.4426950408889634f;   // log2(e)
static constexpr float LN2 = 0.6931471805599453f;   // ln(2)

__device__ __forceinline__ float wave_reduce_sum_f(float v) {
    #pragma unroll
    for (int m = 32; m >= 1; m >>= 1) v += __shfl_xor(v, m, 64);
    return v;
}
__device__ __forceinline__ int wave_reduce_sum_i(int v) {
    #pragma unroll
    for (int m = 32; m >= 1; m >>= 1) v += __shfl_xor(v, m, 64);
    return v;
}

__device__ __forceinline__ int count_L(const void* mask, int b, int lane, unsigned w0) {
    int c = 0;
    if (w0 == 1u) {
        const int* mp = (const int*)mask + (size_t)b * TT;
        for (int t = lane; t < TT; t += 64) c += (mp[t] != 0);
    } else if (w0 == 0x3f800000u) {
        const float* mp = (const float*)mask + (size_t)b * TT;
        for (int t = lane; t < TT; t += 64) c += (mp[t] != 0.0f);
    } else {
        const unsigned char* mp = (const unsigned char*)mask + (size_t)b * TT;
        for (int t = lane; t < TT; t += 64) c += (mp[t] != 0);
    }
    return wave_reduce_sum_i(c);
}

__device__ __forceinline__ f32x4 mfma32(f16x8 a, f16x8 b, f32x4 c) {
    return __builtin_amdgcn_mfma_f32_16x16x32_f16(a, b, c, 0, 0, 0);
}

// max over the 12 per-lane state elements (values are positive; 0 floor harmless)
__device__ __forceinline__ float max12(const f32x4* v) {
    float mx = 0.0f;
    #pragma unroll
    for (int m = 0; m < 3; ++m) {
        #pragma unroll
        for (int e = 0; e < 4; ++e) mx = fmaxf(mx, v[m][e]);
    }
    return mx;
}

// 16 segment-scans of one chain as 16 MFMA columns.
// FWD=0: column c = fwd segment i=c:  u <- E_t .* (M u), t ascending from a.
//        c==0 init exp(start+em[0]); else ones.
// BWD=1: column c = bwd segment i=c+1: u <- M^T (E_t .* u), t descending from t0.
//        c==15 init exp(end); else ones.
// State per step: B(f16) = U * 2^-D (exact power-of-2 ledger, delayed renorm).
// Uniform loop of 'base' steps + 1 epilogue step (predicated LDS overwrite for
// columns of length base+1) — no per-step snapshots, minimal live registers.
template <int BWD>
__device__ void scan_mfma(
    const float* __restrict__ em, const float* __restrict__ transitions,
    const float* __restrict__ start_t, const float* __restrict__ end_t,
    int Lb, int lane, float (*sh_V)[KK], float* sh_D)
{
    const int c = lane & 15;
    const int g = lane >> 4;
    const int i = BWD ? (c + 1) : c;
    const int N = Lb - 1;
    const int base = N / SEG, rem = N % SEG;
    const bool extra = (i < rem);                          // per-lane (column)
    const int len  = base + (extra ? 1 : 0);
    const int a    = 1 + i * base + (extra ? i : rem);     // first step t of segment

    // ---- A fragments (loop-invariant)
    // chunk 0 (K=0..31, x32): elem e -> k = 16*(e>>2) + 4g + (e&3); row j = 16r + c
    f16x8 A0[3];
    #pragma unroll
    for (int r = 0; r < 3; ++r) {
        f16x8 fr;
        #pragma unroll
        for (int e = 0; e < 8; ++e) {
            const int k = 16 * (e >> 2) + 4 * g + (e & 3);
            const int j = 16 * r + c;
            fr[e] = (_Float16)exp2f((BWD ? transitions[k * KK + j]
                                         : transitions[j * KK + k]) * L2E);
        }
        A0[r] = fr;
    }
#if HAVE_X16
    // chunk 1 (K=32..47, x16): elem e -> k = 32 + 4g + e
    f16x4 A1[3];
    #pragma unroll
    for (int r = 0; r < 3; ++r) {
        f16x4 fr;
        #pragma unroll
        for (int e = 0; e < 4; ++e) {
            const int k = 32 + 4 * g + e;
            const int j = 16 * r + c;
            fr[e] = (_Float16)exp2f((BWD ? transitions[k * KK + j]
                                         : transitions[j * KK + k]) * L2E);
        }
        A1[r] = fr;
    }
#else
    // chunk 1 zero-padded to K=32
    f16x8 A1[3];
    #pragma unroll
    for (int r = 0; r < 3; ++r) {
        f16x8 fr;
        #pragma unroll
        for (int e = 0; e < 8; ++e) {
            const int k = 32 + 16 * (e >> 2) + 4 * g + (e & 3);
            const int j = 16 * r + c;
            float tv = 0.0f;
            if (k < KK)
                tv = exp2f((BWD ? transitions[k * KK + j]
                                : transitions[j * KK + k]) * L2E);
            fr[e] = (_Float16)tv;
        }
        A1[r] = fr;
    }
#endif

    const int t0 = a + len - 1;
    const float* pe = em + (size_t)(BWD ? t0 : a) * KK + 4 * g;  // +16*m per chunk
    const int pstep = BWD ? -KK : KK;

    // ---- init state Braw (rows k = 16*m + 4g + e, col c)
    f32x4 braw[3];
    #pragma unroll
    for (int m = 0; m < 3; ++m) {
        f32x4 bv;
        #pragma unroll
        for (int e = 0; e < 4; ++e) {
            const int k = 16 * m + 4 * g + e;
            float u0;
            if (BWD) u0 = (c == 15) ? exp2f(end_t[k] * L2E) : 1.0f;
            else     u0 = (c == 0) ? exp2f((start_t[k] + em[k]) * L2E) : 1.0f;
            bv[e] = u0;
        }
        braw[m] = bv;
    }
    if (BWD) {   // bwd folds E at t0 into the init state
        #pragma unroll
        for (int m = 0; m < 3; ++m) {
            const f32x4 ev = *(const f32x4*)(pe + 16 * m);
            #pragma unroll
            for (int e = 0; e < 4; ++e) braw[m][e] *= exp2f(ev[e] * L2E);
        }
        pe += pstep;                       // now at tE(1) = t0-1
    }

    // emission for step 1 (fwd: t=a; bwd: t=t0-1)
    f32x4 cur[3], nxt[3];
    #pragma unroll
    for (int m = 0; m < 3; ++m) cur[m] = *(const f32x4*)(pe + 16 * m);
    pe += pstep;

    int D = 0, Dprev = 0;
    float mx = max12(braw);
    mx = fmaxf(mx, __shfl_xor(mx, 16));
    mx = fmaxf(mx, __shfl_xor(mx, 32));
    int dadj = (int)((__float_as_uint(mx) >> 23) & 0xFF) - 127 + CENTER;

    // pack braw -> B fragments (in-lane: C/D row 16m+4g+e == B k-slot mapping)
    f16x8 B0;
#if HAVE_X16
    f16x4 B1;
#else
    f16x8 B1;
#endif
    {
        B0 = (f16x8){(_Float16)braw[0][0], (_Float16)braw[0][1],
                     (_Float16)braw[0][2], (_Float16)braw[0][3],
                     (_Float16)braw[1][0], (_Float16)braw[1][1],
                     (_Float16)braw[1][2], (_Float16)braw[1][3]};
#if HAVE_X16
        B1 = (f16x4){(_Float16)braw[2][0], (_Float16)braw[2][1],
                     (_Float16)braw[2][2], (_Float16)braw[2][3]};
#else
        B1 = (f16x8){(_Float16)braw[2][0], (_Float16)braw[2][1],
                     (_Float16)braw[2][2], (_Float16)braw[2][3],
                     (_Float16)0, (_Float16)0, (_Float16)0, (_Float16)0};
#endif
    }

    f32x4 C[3];

    #pragma unroll 1
    for (int s = 1; s <= base; ++s) {
        // prefetch emission for step s+1 (in-bounds by construction)
        #pragma unroll
        for (int m = 0; m < 3; ++m) nxt[m] = *(const f32x4*)(pe + 16 * m);
        pe += pstep;

        // C = M (fwd) / M^T (bwd) times B
        #pragma unroll
        for (int r = 0; r < 3; ++r) {
            f32x4 z = {0.0f, 0.0f, 0.0f, 0.0f};
            z = mfma32(A0[r], B0, z);
#if HAVE_X16
            z = __builtin_amdgcn_mfma_f32_16x16x16f16(A1[r], B1, z, 0, 0, 0);
#else
            z = mfma32(A1[r], B1, z);
#endif
            C[r] = z;
        }

        // renorm + E-fold (delayed normalizer, exact power-of-2 ledger)
        const float nd = -(float)dadj;
        #pragma unroll
        for (int m = 0; m < 3; ++m) {
            #pragma unroll
            for (int e = 0; e < 4; ++e)
                braw[m][e] = C[m][e] * exp2f(fmaf(cur[m][e], L2E, nd));
        }
        Dprev = D;
        D += dadj;
        float mx2 = max12(braw);
        mx2 = fmaxf(mx2, __shfl_xor(mx2, 16));
        mx2 = fmaxf(mx2, __shfl_xor(mx2, 32));
        dadj = (int)((__float_as_uint(mx2) >> 23) & 0xFF) - 127 + CENTER;

        B0 = (f16x8){(_Float16)braw[0][0], (_Float16)braw[0][1],
                     (_Float16)braw[0][2], (_Float16)braw[0][3],
                     (_Float16)braw[1][0], (_Float16)braw[1][1],
                     (_Float16)braw[1][2], (_Float16)braw[1][3]};
#if HAVE_X16
        B1 = (f16x4){(_Float16)braw[2][0], (_Float16)braw[2][1],
                     (_Float16)braw[2][2], (_Float16)braw[2][3]};
#else
        B1 = (f16x8){(_Float16)braw[2][0], (_Float16)braw[2][1],
                     (_Float16)braw[2][2], (_Float16)braw[2][3],
                     (_Float16)0, (_Float16)0, (_Float16)0, (_Float16)0};
#endif

        #pragma unroll
        for (int m = 0; m < 3; ++m) cur[m] = nxt[m];
    }

    // ---- phase 1: all columns output state after 'base' steps
    // BWD: beta = C (ledger Dprev, pre last update). FWD: braw (ledger D).
    #pragma unroll
    for (int r = 0; r < 3; ++r) {
        #pragma unroll
        for (int e = 0; e < 4; ++e)
            sh_V[c][16 * r + 4 * g + e] = BWD ? C[r][e] : braw[r][e];
    }
    if (g == 0) sh_D[c] = (float)(BWD ? Dprev : D);

    // ---- epilogue: one more step; overwrite only columns with len = base+1
    #pragma unroll
    for (int r = 0; r < 3; ++r) {
        f32x4 z = {0.0f, 0.0f, 0.0f, 0.0f};
        z = mfma32(A0[r], B0, z);
#if HAVE_X16
        z = __builtin_amdgcn_mfma_f32_16x16x16f16(A1[r], B1, z, 0, 0, 0);
#else
        z = mfma32(A1[r], B1, z);
#endif
        C[r] = z;
    }
    float Dx;
    if (BWD) {
        Dx = (float)D;
    } else {
        const float nd = -(float)dadj;
        #pragma unroll
        for (int m = 0; m < 3; ++m) {
            #pragma unroll
            for (int e = 0; e < 4; ++e)
                C[m][e] = C[m][e] * exp2f(fmaf(cur[m][e], L2E, nd));
        }
        Dx = (float)(D + dadj);
    }
    if (extra) {
        #pragma unroll
        for (int r = 0; r < 3; ++r) {
            #pragma unroll
            for (int e = 0; e < 4; ++e)
                sh_V[c][16 * r + 4 * g + e] = C[r][e];
        }
        if (g == 0) sh_D[c] = Dx;
    }
}

// One block per batch element, 3 waves: fwd-scan wave, bwd-scan wave, numerator wave.
// Splice: den = (m1.x) * prod_i (m_{i+1}.p_i) * (y.p_{S-2}) / prod_i (1.p_i)
__global__ __launch_bounds__(192, 1) void crf_all(
    const float* __restrict__ emissions,   // (B, T, K)
    const int*   __restrict__ tags,        // (B, T)
    const void*  __restrict__ mask,        // (B, T) — dtype probed
    const float* __restrict__ transitions, // (K, K)
    const float* __restrict__ start_t,     // (K,)
    const float* __restrict__ end_t,       // (K,)
    float*       __restrict__ out)         // (B,)
{
    const int b    = blockIdx.x;
    const int wid  = threadIdx.x >> 6;
    const int lane = threadIdx.x & 63;
    __shared__ float sh_F[16][KK];
    __shared__ float sh_G[16][KK];
    __shared__ float sh_DF[16];
    __shared__ float sh_DG[16];
    __shared__ float sh_sc;

    const unsigned w0 = *((const unsigned*)mask);
    const int L = count_L(mask, b, lane, w0);
    const float* em = emissions + (size_t)b * TT * KK;

    if (wid == 0) {
        scan_mfma<0>(em, transitions, start_t, end_t, L, lane, sh_F, sh_DF);
    } else if (wid == 1) {
        scan_mfma<1>(em, transitions, start_t, end_t, L, lane, sh_G, sh_DG);
    } else {
        // numerator (verbatim from passing rounds)
        const int* tg = tags + (size_t)b * TT;
        float sc = 0.0f;
        for (int t = lane; t < TT; t += 64) {
            if (t < L) {
                const int tagt = tg[t];
                float term = em[(size_t)t * KK + tagt];
                term += (t == 0) ? start_t[tagt] : transitions[tg[t - 1] * KK + tagt];
                sc += term;
            }
        }
        sc = wave_reduce_sum_f(sc);
        if (lane == 0) sh_sc = sc + end_t[tg[L - 1]];
    }
    __syncthreads();

    if (wid == 0) {
        // acc = sum_k [log2(G_k.F_k) + DG_k] - sum_{k>=1} log2(1.F_k)  (DF_k cancels, k>=1)
        const int k = lane >> 2;
        const int q = lane & 3;
        float dot = 0.0f, ns = 0.0f;
        #pragma unroll
        for (int e = 0; e < 12; ++e) {
            const int j = q * 12 + e;
            const float f = sh_F[k][j];
            dot += sh_G[k][j] * f;
            ns  += f;
        }
        dot += __shfl_xor(dot, 1, 64); dot += __shfl_xor(dot, 2, 64);
        ns  += __shfl_xor(ns, 1, 64);  ns  += __shfl_xor(ns, 2, 64);
        float v = 0.0f;
        if (q == 0) {
            v = log2f(dot) + sh_DG[k];
            if (k >= 1) v -= log2f(ns);
        }
        const float acc = wave_reduce_sum_f(v);
        if (lane == 0) out[b] = sh_sc - LN2 * (acc + sh_DF[0]);
    }
}

extern "C" void kernel_launch(void* const* d_in, const int* in_sizes, int n_in,
                              void* d_out, int out_size, void* d_ws, size_t ws_size,
                              hipStream_t stream) {
    const float* emissions   = (const float*)d_in[0];
    const int*   tags        = (const int*)  d_in[1];
    const void*  mask        = (const void*) d_in[2];
    const float* transitions = (const float*)d_in[3];
    const float* start_t     = (const float*)d_in[4];
    const float* end_t       = (const float*)d_in[5];
    float* out = (float*)d_out;
    (void)d_ws; (void)ws_size;

    crf_all<<<BB, 192, 0, stream>>>(emissions, tags, mask, transitions,
                                    start_t, end_t, out);
}

// Round 7
// 171.963 us; speedup vs baseline: 1.0859x; 1.0859x over previous
//
#include <hip/hip_runtime.h>
#include <math.h>

#define BB 512
#define TT 1024
#define KK 48
#define SEG 33       // segments per chain; 32 fwd + 32 bwd columns = 2 waves/direction
#define PF 4         // emission prefetch ring depth (steps)
#define CENTER 6     // keep |B| centered near 2^-CENTER for f16 headroom

typedef _Float16 f16x8 __attribute__((ext_vector_type(8)));
typedef _Float16 f16x4 __attribute__((ext_vector_type(4)));
typedef float    f32x4 __attribute__((ext_vector_type(4)));

#if __has_builtin(__builtin_amdgcn_mfma_f32_16x16x16f16)
#define HAVE_X16 1
#else
#define HAVE_X16 0
#endif

static constexpr float L2E = 1.4426950408889634f;   // log2(e)
static constexpr float LN2 = 0.6931471805599453f;   // ln(2)

__device__ __forceinline__ float wave_reduce_sum_f(float v) {
    #pragma unroll
    for (int m = 32; m >= 1; m >>= 1) v += __shfl_xor(v, m, 64);
    return v;
}
__device__ __forceinline__ int wave_reduce_sum_i(int v) {
    #pragma unroll
    for (int m = 32; m >= 1; m >>= 1) v += __shfl_xor(v, m, 64);
    return v;
}

__device__ __forceinline__ int count_L(const void* mask, int b, int lane, unsigned w0) {
    int c = 0;
    if (w0 == 1u) {
        const int* mp = (const int*)mask + (size_t)b * TT;
        for (int t = lane; t < TT; t += 64) c += (mp[t] != 0);
    } else if (w0 == 0x3f800000u) {
        const float* mp = (const float*)mask + (size_t)b * TT;
        for (int t = lane; t < TT; t += 64) c += (mp[t] != 0.0f);
    } else {
        const unsigned char* mp = (const unsigned char*)mask + (size_t)b * TT;
        for (int t = lane; t < TT; t += 64) c += (mp[t] != 0);
    }
    return wave_reduce_sum_i(c);
}

__device__ __forceinline__ f32x4 mfma32(f16x8 a, f16x8 b, f32x4 c) {
    return __builtin_amdgcn_mfma_f32_16x16x32_f16(a, b, c, 0, 0, 0);
}

// max over the 12 per-lane state elements (values are positive; 0 floor harmless)
__device__ __forceinline__ float max12(const f32x4* v) {
    float mx = 0.0f;
    #pragma unroll
    for (int m = 0; m < 3; ++m) {
        #pragma unroll
        for (int e = 0; e < 4; ++e) mx = fmaxf(mx, v[m][e]);
    }
    return mx;
}

// 16 segment-scans (columns) of one chain per wave; two waves per direction.
// FWD=0: column = segment i = wofs+c:  u <- E_t .* (M u), t ascending from a.
//        i==0 init exp(start+em[0]); else ones.
// BWD=1: column = segment i = wofs+c+1: u <- M^T (E_t .* u), t descending from t0.
//        i==SEG-1 init exp(end); else ones.
// State: B(f16) = U * 2^-D (exact power-of-2 ledger, delayed renorm).
// Uniform loop of 'base' steps (PF-deep register prefetch ring) + leftover +
// 1 epilogue step (predicated LDS overwrite for columns of length base+1).
template <int BWD>
__device__ void scan_mfma(
    const float* __restrict__ em, const float* __restrict__ transitions,
    const float* __restrict__ start_t, const float* __restrict__ end_t,
    int Lb, int lane, int wofs, float (*sh_V)[KK], float* sh_D)
{
    const int c = lane & 15;
    const int g = lane >> 4;
    const int i = wofs + c + (BWD ? 1 : 0);
    const int N = Lb - 1;
    const int base = N / SEG, rem = N % SEG;
    const bool extra = (i < rem);                          // per-lane (column)
    const int len  = base + (extra ? 1 : 0);
    const int a    = 1 + i * base + (extra ? i : rem);     // first step t of segment
    const int t0   = a + len - 1;

    // ---- A fragments (loop-invariant)
    // chunk 0 (K=0..31, x32): elem e -> k = 16*(e>>2) + 4g + (e&3); row j = 16r + c
    f16x8 A0[3];
    #pragma unroll
    for (int r = 0; r < 3; ++r) {
        f16x8 fr;
        #pragma unroll
        for (int e = 0; e < 8; ++e) {
            const int k = 16 * (e >> 2) + 4 * g + (e & 3);
            const int j = 16 * r + c;
            fr[e] = (_Float16)exp2f((BWD ? transitions[k * KK + j]
                                         : transitions[j * KK + k]) * L2E);
        }
        A0[r] = fr;
    }
#if HAVE_X16
    f16x4 A1[3];
    #pragma unroll
    for (int r = 0; r < 3; ++r) {
        f16x4 fr;
        #pragma unroll
        for (int e = 0; e < 4; ++e) {
            const int k = 32 + 4 * g + e;
            const int j = 16 * r + c;
            fr[e] = (_Float16)exp2f((BWD ? transitions[k * KK + j]
                                         : transitions[j * KK + k]) * L2E);
        }
        A1[r] = fr;
    }
#else
    f16x8 A1[3];
    #pragma unroll
    for (int r = 0; r < 3; ++r) {
        f16x8 fr;
        #pragma unroll
        for (int e = 0; e < 8; ++e) {
            const int k = 32 + 16 * (e >> 2) + 4 * g + (e & 3);
            const int j = 16 * r + c;
            float tv = 0.0f;
            if (k < KK)
                tv = exp2f((BWD ? transitions[k * KK + j]
                                : transitions[j * KK + k]) * L2E);
            fr[e] = (_Float16)tv;
        }
        A1[r] = fr;
    }
#endif

    // ---- init state Braw (rows k = 16*m + 4g + e, col c)
    f32x4 braw[3];
    #pragma unroll
    for (int m = 0; m < 3; ++m) {
        f32x4 bv;
        #pragma unroll
        for (int e = 0; e < 4; ++e) {
            const int k = 16 * m + 4 * g + e;
            float u0;
            if (BWD) u0 = (i == SEG - 1) ? exp2f(end_t[k] * L2E) : 1.0f;
            else     u0 = (i == 0) ? exp2f((start_t[k] + em[k]) * L2E) : 1.0f;
            bv[e] = u0;
        }
        braw[m] = bv;
    }
    if (BWD) {   // bwd folds E at t0 into the init state
        const float* p0 = em + (size_t)t0 * KK + 4 * g;
        #pragma unroll
        for (int m = 0; m < 3; ++m) {
            const f32x4 ev = *(const f32x4*)(p0 + 16 * m);
            #pragma unroll
            for (int e = 0; e < 4; ++e) braw[m][e] *= exp2f(ev[e] * L2E);
        }
    }

    // ---- preload ring: buf[k] = E(step 1+k)  (fwd t=a+k; bwd t=t0-1-k)
    f32x4 buf[PF][3];
    #pragma unroll
    for (int k = 0; k < PF; ++k) {
        int t = BWD ? (t0 - 1 - k) : (a + k);
        t = t < 0 ? 0 : (t > TT - 1 ? TT - 1 : t);
        const float* p = em + (size_t)t * KK + 4 * g;
        #pragma unroll
        for (int m = 0; m < 3; ++m) buf[k][m] = *(const f32x4*)(p + 16 * m);
    }

    int D = 0, Dprev = 0;
    float mx = max12(braw);
    mx = fmaxf(mx, __shfl_xor(mx, 16));
    mx = fmaxf(mx, __shfl_xor(mx, 32));
    int dadj = (int)((__float_as_uint(mx) >> 23) & 0xFF) - 127 + CENTER;

    f16x8 B0;
#if HAVE_X16
    f16x4 B1;
#else
    f16x8 B1;
#endif
    B0 = (f16x8){(_Float16)braw[0][0], (_Float16)braw[0][1],
                 (_Float16)braw[0][2], (_Float16)braw[0][3],
                 (_Float16)braw[1][0], (_Float16)braw[1][1],
                 (_Float16)braw[1][2], (_Float16)braw[1][3]};
#if HAVE_X16
    B1 = (f16x4){(_Float16)braw[2][0], (_Float16)braw[2][1],
                 (_Float16)braw[2][2], (_Float16)braw[2][3]};
#else
    B1 = (f16x8){(_Float16)braw[2][0], (_Float16)braw[2][1],
                 (_Float16)braw[2][2], (_Float16)braw[2][3],
                 (_Float16)0, (_Float16)0, (_Float16)0, (_Float16)0};
#endif

    f32x4 C[3];

    auto STEP = [&](const f32x4* E) {
        #pragma unroll
        for (int r = 0; r < 3; ++r) {
            f32x4 z = {0.0f, 0.0f, 0.0f, 0.0f};
            z = mfma32(A0[r], B0, z);
#if HAVE_X16
            z = __builtin_amdgcn_mfma_f32_16x16x16f16(A1[r], B1, z, 0, 0, 0);
#else
            z = mfma32(A1[r], B1, z);
#endif
            C[r] = z;
        }
        const float nd = -(float)dadj;
        #pragma unroll
        for (int m = 0; m < 3; ++m) {
            #pragma unroll
            for (int e = 0; e < 4; ++e)
                braw[m][e] = C[m][e] * exp2f(fmaf(E[m][e], L2E, nd));
        }
        Dprev = D;
        D += dadj;
        float mx2 = max12(braw);
        mx2 = fmaxf(mx2, __shfl_xor(mx2, 16));
        mx2 = fmaxf(mx2, __shfl_xor(mx2, 32));
        dadj = (int)((__float_as_uint(mx2) >> 23) & 0xFF) - 127 + CENTER;
        B0 = (f16x8){(_Float16)braw[0][0], (_Float16)braw[0][1],
                     (_Float16)braw[0][2], (_Float16)braw[0][3],
                     (_Float16)braw[1][0], (_Float16)braw[1][1],
                     (_Float16)braw[1][2], (_Float16)braw[1][3]};
#if HAVE_X16
        B1 = (f16x4){(_Float16)braw[2][0], (_Float16)braw[2][1],
                     (_Float16)braw[2][2], (_Float16)braw[2][3]};
#else
        B1 = (f16x8){(_Float16)braw[2][0], (_Float16)braw[2][1],
                     (_Float16)braw[2][2], (_Float16)braw[2][3],
                     (_Float16)0, (_Float16)0, (_Float16)0, (_Float16)0};
#endif
    };

    // ---- main loop: full batches of PF steps; refill ring PF steps ahead
    int sb = 1;
    int tn = BWD ? (t0 - 1 - PF) : (a + PF);   // t of step sb+PF (next fill, k=0)
    #pragma unroll 1
    for (; sb + PF - 1 <= base; sb += PF) {
        #pragma unroll
        for (int k = 0; k < PF; ++k) {
            STEP(buf[k]);                       // step sb+k
            int t = tn + (BWD ? -k : k);        // fill for step sb+PF+k
            t = t < 0 ? 0 : (t > TT - 1 ? TT - 1 : t);
            const float* p = em + (size_t)t * KK + 4 * g;
            #pragma unroll
            for (int m = 0; m < 3; ++m) buf[k][m] = *(const f32x4*)(p + 16 * m);
        }
        tn += BWD ? -PF : PF;
    }
    // leftover steps sb..base (lsteps uniform, 0..PF-1)
    const int lsteps = base - sb + 1;
    #pragma unroll
    for (int k = 0; k < PF - 1; ++k)
        if (k < lsteps) STEP(buf[k]);

    // ---- phase 1: all columns output state after 'base' steps
    // BWD: beta = C (ledger Dprev, pre last update). FWD: braw (ledger D).
    const int slot = wofs + c;
    #pragma unroll
    for (int r = 0; r < 3; ++r) {
        #pragma unroll
        for (int e = 0; e < 4; ++e)
            sh_V[slot][16 * r + 4 * g + e] = BWD ? C[r][e] : braw[r][e];
    }
    if (g == 0) sh_D[slot] = (float)(BWD ? Dprev : D);

    // ---- epilogue: one more step; overwrite only columns with len = base+1
    // E for step base+1 is buf[lsteps] (static 4-way select; uniform condition)
    f32x4 epE[3];
    #pragma unroll
    for (int k = 0; k < PF; ++k) {
        if (k == lsteps) {
            epE[0] = buf[k][0]; epE[1] = buf[k][1]; epE[2] = buf[k][2];
        }
    }
    #pragma unroll
    for (int r = 0; r < 3; ++r) {
        f32x4 z = {0.0f, 0.0f, 0.0f, 0.0f};
        z = mfma32(A0[r], B0, z);
#if HAVE_X16
        z = __builtin_amdgcn_mfma_f32_16x16x16f16(A1[r], B1, z, 0, 0, 0);
#else
        z = mfma32(A1[r], B1, z);
#endif
        C[r] = z;
    }
    float Dx;
    if (BWD) {
        Dx = (float)D;
    } else {
        const float nd = -(float)dadj;
        #pragma unroll
        for (int m = 0; m < 3; ++m) {
            #pragma unroll
            for (int e = 0; e < 4; ++e)
                C[m][e] = C[m][e] * exp2f(fmaf(epE[m][e], L2E, nd));
        }
        Dx = (float)(D + dadj);
    }
    if (extra) {
        #pragma unroll
        for (int r = 0; r < 3; ++r) {
            #pragma unroll
            for (int e = 0; e < 4; ++e)
                sh_V[slot][16 * r + 4 * g + e] = C[r][e];
        }
        if (g == 0) sh_D[slot] = Dx;
    }
}

// One block per batch element, 5 waves: 2 fwd-scan, 2 bwd-scan, 1 numerator.
// Splice: den = (m1.x) * prod_i (m_{i+1}.p_i) * (y.p_{S-2}) / prod_i (1.p_i)
__global__ __launch_bounds__(320, 1) void crf_all(
    const float* __restrict__ emissions,   // (B, T, K)
    const int*   __restrict__ tags,        // (B, T)
    const void*  __restrict__ mask,        // (B, T) — dtype probed
    const float* __restrict__ transitions, // (K, K)
    const float* __restrict__ start_t,     // (K,)
    const float* __restrict__ end_t,       // (K,)
    float*       __restrict__ out)         // (B,)
{
    const int b    = blockIdx.x;
    const int wid  = threadIdx.x >> 6;
    const int lane = threadIdx.x & 63;
    __shared__ float sh_F[SEG - 1][KK];
    __shared__ float sh_G[SEG - 1][KK];
    __shared__ float sh_DF[SEG - 1];
    __shared__ float sh_DG[SEG - 1];
    __shared__ float sh_sc;

    const unsigned w0 = *((const unsigned*)mask);
    const int L = count_L(mask, b, lane, w0);
    const float* em = emissions + (size_t)b * TT * KK;

    if (wid < 2) {
        scan_mfma<0>(em, transitions, start_t, end_t, L, lane, wid * 16, sh_F, sh_DF);
    } else if (wid < 4) {
        scan_mfma<1>(em, transitions, start_t, end_t, L, lane, (wid - 2) * 16, sh_G, sh_DG);
    } else {
        // numerator (verbatim from passing rounds)
        const int* tg = tags + (size_t)b * TT;
        float sc = 0.0f;
        for (int t = lane; t < TT; t += 64) {
            if (t < L) {
                const int tagt = tg[t];
                float term = em[(size_t)t * KK + tagt];
                term += (t == 0) ? start_t[tagt] : transitions[tg[t - 1] * KK + tagt];
                sc += term;
            }
        }
        sc = wave_reduce_sum_f(sc);
        if (lane == 0) sh_sc = sc + end_t[tg[L - 1]];
    }
    __syncthreads();

    if (wid == 0) {
        // acc = sum_k [log2(G_k.F_k) + DG_k] - sum_{k>=1} log2(1.F_k)  (DF_k cancels, k>=1)
        const int k = lane >> 1;          // column 0..31
        const int q = lane & 1;
        float dot = 0.0f, ns = 0.0f;
        #pragma unroll
        for (int e = 0; e < 24; ++e) {
            const int j = q * 24 + e;
            const float f = sh_F[k][j];
            dot += sh_G[k][j] * f;
            ns  += f;
        }
        dot += __shfl_xor(dot, 1, 64);
        ns  += __shfl_xor(ns, 1, 64);
        float v = 0.0f;
        if (q == 0) {
            v = log2f(dot) + sh_DG[k];
            if (k >= 1) v -= log2f(ns);
        }
        const float acc = wave_reduce_sum_f(v);
        if (lane == 0) out[b] = sh_sc - LN2 * (acc + sh_DF[0]);
    }
}

extern "C" void kernel_launch(void* const* d_in, const int* in_sizes, int n_in,
                              void* d_out, int out_size, void* d_ws, size_t ws_size,
                              hipStream_t stream) {
    const float* emissions   = (const float*)d_in[0];
    const int*   tags        = (const int*)  d_in[1];
    const void*  mask        = (const void*) d_in[2];
    const float* transitions = (const float*)d_in[3];
    const float* start_t     = (const float*)d_in[4];
    const float* end_t       = (const float*)d_in[5];
    float* out = (float*)d_out;
    (void)d_ws; (void)ws_size;

    crf_all<<<BB, 320, 0, stream>>>(emissions, tags, mask, transitions,
                                    start_t, end_t, out);
}